// Round 1
// baseline (624.706 us; speedup 1.0000x reference)
//
#include <hip/hip_runtime.h>
#include <stdint.h>

// Segmented cumprod (NeRF ray accumulation) via single-pass decoupled-lookback
// segmented scan. n = 16.7M samples, sorted ray_id => contiguous segments.
// Combine op: (va,fa) (+) (vb,fb) = (fb ? vb : va*vb, fa|fb)   [associative]

#define BLOCK 256
#define PER_THREAD 16
#define CHUNK (BLOCK * PER_THREAD)

#define ST_INVALID 0
#define ST_PARTIAL 1
#define ST_PREFIX  2

struct Pair { float v; int f; };

__device__ __forceinline__ Pair seg_combine(Pair a, Pair b) {
    Pair r;
    r.v = b.f ? b.v : (a.v * b.v);
    r.f = a.f | b.f;
    return r;
}

__device__ __forceinline__ uint64_t pack_agg(float v, int f, int st) {
    return (uint64_t)__float_as_uint(v) | (((uint64_t)((uint32_t)(st | (f << 2)))) << 32);
}
__device__ __forceinline__ void unpack_agg(uint64_t p, float& v, int& f, int& st) {
    v  = __uint_as_float((uint32_t)p);
    uint32_t hi = (uint32_t)(p >> 32);
    st = (int)(hi & 3u);
    f  = (int)((hi >> 2) & 1u);
}

// Init: alphainv_last[r] = cumprod[0] = (1-alpha[0])+1e-11 (covers empty rays;
// rays with samples get overwritten by the seg-end scatter). Also zero the
// lookback descriptors (d_ws is re-poisoned to 0xAA before every launch).
__global__ void nerf_init(const float* __restrict__ alpha,
                          float* __restrict__ alphainv, int N_ray,
                          uint64_t* __restrict__ agg, int nchunks) {
    int i = blockIdx.x * blockDim.x + threadIdx.x;
    float c0 = (1.0f - alpha[0]) + 1e-11f;
    if (i < N_ray)  alphainv[i] = c0;
    if (i < nchunks) agg[i] = 0ull;
}

__global__ __launch_bounds__(BLOCK)
void nerf_main(const float* __restrict__ alpha, const int* __restrict__ ray_id,
               float* __restrict__ weights, float* __restrict__ alphainv,
               uint64_t* __restrict__ agg, int n) {
    __shared__ float s_v[BLOCK];
    __shared__ int   s_f[BLOCK];
    __shared__ float s_pv;
    __shared__ int   s_pf;

    const int c = blockIdx.x;
    const int t = threadIdx.x;
    const long gstart = (long)c * CHUNK + (long)t * PER_THREAD;

    float a[PER_THREAD];
    int   rid[PER_THREAD];
    const bool full = (gstart + PER_THREAD) <= (long)n;

    if (full) {
        #pragma unroll
        for (int k = 0; k < PER_THREAD / 4; ++k) {
            float4 av = *(const float4*)(alpha  + gstart + 4 * k);
            int4   rv = *(const int4*)  (ray_id + gstart + 4 * k);
            a[4*k+0] = av.x; a[4*k+1] = av.y; a[4*k+2] = av.z; a[4*k+3] = av.w;
            rid[4*k+0] = rv.x; rid[4*k+1] = rv.y; rid[4*k+2] = rv.z; rid[4*k+3] = rv.w;
        }
    } else {
        #pragma unroll
        for (int k = 0; k < PER_THREAD; ++k) {
            long g = gstart + k;
            a[k]   = (g < n) ? alpha[g]  : 0.0f;
            rid[k] = (g < n) ? ray_id[g] : -2;
        }
    }
    // previous ray id (for is_start); element after my last (for seg-end)
    int rid_prev = (gstart > 0 && gstart < n) ? ray_id[gstart - 1] : -1;
    int rid_next = ((gstart + PER_THREAD) < (long)n) ? ray_id[gstart + PER_THREAD] : -1;

    // ---- thread-local sequential segmented scan over 16 elems ----
    float om[PER_THREAD];
    int   sflag[PER_THREAD];
    Pair run; run.v = 1.0f; run.f = 0;
    int prev = rid_prev;
    #pragma unroll
    for (int k = 0; k < PER_THREAD; ++k) {
        bool inb = (gstart + k) < (long)n;
        om[k]    = inb ? ((1.0f - a[k]) + 1e-11f) : 1.0f;   // identity if OOB
        sflag[k] = inb ? (rid[k] != prev ? 1 : 0) : 0;
        prev = rid[k];
        Pair e; e.v = om[k]; e.f = sflag[k];
        run = seg_combine(run, e);
    }

    // ---- block-level Hillis-Steele inclusive scan (non-commutative-safe) ----
    s_v[t] = run.v; s_f[t] = run.f;
    __syncthreads();
    Pair val = run;
    #pragma unroll
    for (int off = 1; off < BLOCK; off <<= 1) {
        Pair other; other.v = 1.0f; other.f = 0;
        bool has = (t >= off);
        if (has) { other.v = s_v[t - off]; other.f = s_f[t - off]; }
        __syncthreads();
        if (has) {
            val = seg_combine(other, val);
            s_v[t] = val.v; s_f[t] = val.f;
        }
        __syncthreads();
    }
    // s_v[BLOCK-1] = chunk aggregate; s_v[t] = inclusive over threads [0..t]

    // ---- decoupled lookback (thread 0) ----
    if (t == 0) {
        Pair bag; bag.v = s_v[BLOCK - 1]; bag.f = s_f[BLOCK - 1];
        __hip_atomic_store(&agg[c], pack_agg(bag.v, bag.f, ST_PARTIAL),
                           __ATOMIC_RELEASE, __HIP_MEMORY_SCOPE_AGENT);
        Pair pre; pre.v = 1.0f; pre.f = 0;
        if (c > 0) {
            Pair acc; acc.v = 1.0f; acc.f = 0;
            int have = 0;
            for (int j = c - 1; j >= 0; --j) {
                float v; int f, st;
                for (;;) {
                    uint64_t p = __hip_atomic_load(&agg[j], __ATOMIC_ACQUIRE,
                                                   __HIP_MEMORY_SCOPE_AGENT);
                    unpack_agg(p, v, f, st);
                    if (st != ST_INVALID) break;
                    __builtin_amdgcn_s_sleep(1);
                }
                Pair e; e.v = v; e.f = f;
                acc = have ? seg_combine(e, acc) : e;
                have = 1;
                if (st == ST_PREFIX || acc.f) break;  // avg seg len 256 << CHUNK => depth ~1
            }
            pre = acc;
        }
        Pair inc = seg_combine(pre, bag);
        __hip_atomic_store(&agg[c], pack_agg(inc.v, inc.f, ST_PREFIX),
                           __ATOMIC_RELEASE, __HIP_MEMORY_SCOPE_AGENT);
        s_pv = pre.v; s_pf = pre.f;
    }
    __syncthreads();

    // ---- apply: exclusive running value at i == cumprod[i-1] == transmittance ----
    Pair chunk_pre; chunk_pre.v = s_pv; chunk_pre.f = s_pf;
    Pair excl;
    if (t == 0) { excl.v = 1.0f; excl.f = 0; }
    else        { excl.v = s_v[t - 1]; excl.f = s_f[t - 1]; }
    Pair run2 = seg_combine(chunk_pre, excl);

    float w[PER_THREAD];
    #pragma unroll
    for (int k = 0; k < PER_THREAD; ++k) {
        float trans = run2.v;                 // cumprod[i-1] (global shift; =1 at i==0)
        Pair e; e.v = om[k]; e.f = sflag[k];
        run2 = seg_combine(run2, e);          // run2.v = cumprod[i]
        w[k] = a[k] * trans;
        bool inb = (gstart + k) < (long)n;
        int nxt = (k + 1 < PER_THREAD) ? rid[k + 1] : rid_next;
        bool seg_end = inb && (nxt != rid[k]);
        if (seg_end) alphainv[rid[k]] = run2.v;  // one writer per ray (sorted ids)
    }

    if (full) {
        #pragma unroll
        for (int k = 0; k < PER_THREAD / 4; ++k) {
            float4 wv; wv.x = w[4*k+0]; wv.y = w[4*k+1]; wv.z = w[4*k+2]; wv.w = w[4*k+3];
            *(float4*)(weights + gstart + 4 * k) = wv;
        }
    } else {
        for (int k = 0; k < PER_THREAD; ++k) {
            long g = gstart + k;
            if (g < n) weights[g] = w[k];
        }
    }
}

extern "C" void kernel_launch(void* const* d_in, const int* in_sizes, int n_in,
                              void* d_out, int out_size, void* d_ws, size_t ws_size,
                              hipStream_t stream) {
    const float* alpha  = (const float*)d_in[0];
    const int*   ray_id = (const int*)d_in[1];
    const int n     = in_sizes[0];
    const int N_ray = out_size - n;          // avoids device read of d_in[2]

    float* weights  = (float*)d_out;
    float* alphainv = (float*)d_out + n;
    uint64_t* agg   = (uint64_t*)d_ws;       // nchunks * 8B lookback descriptors

    const int nchunks = (n + CHUNK - 1) / CHUNK;
    int init_items = (N_ray > nchunks) ? N_ray : nchunks;
    int init_blocks = (init_items + BLOCK - 1) / BLOCK;

    nerf_init<<<init_blocks, BLOCK, 0, stream>>>(alpha, alphainv, N_ray, agg, nchunks);
    nerf_main<<<nchunks, BLOCK, 0, stream>>>(alpha, ray_id, weights, alphainv, agg, n);
}

// Round 2
// 192.273 us; speedup vs baseline: 3.2491x; 3.2491x over previous
//
#include <hip/hip_runtime.h>
#include <stdint.h>

// NeRF segmented cumprod — two-pass reduce-then-scan. No atomics, no spins,
// no inter-block communication inside a kernel. Chunk prefix in pass 2 is a
// plain backward read of pass-1 aggregates, terminated at the first segment
// reset flag (avg segment len 256 << CHUNK 4096 => depth ~1).
//
// Combine op (associative, NON-commutative):
//   (va,fa) (+) (vb,fb) = (fb ? vb : va*vb, fa|fb)

#define BLOCK 256
#define PER_THREAD 16
#define CHUNK (BLOCK * PER_THREAD)
#define NWAVE (BLOCK / 64)

struct Pair { float v; int f; };

__device__ __forceinline__ Pair seg_combine(Pair a, Pair b) {
    Pair r;
    r.v = b.f ? b.v : (a.v * b.v);
    r.f = a.f | b.f;
    return r;
}

// ---------------------------------------------------------------------------
// Pass 1: per-chunk segmented aggregate (+ alphainv init for empty rays).
// Pure streaming read; one float2 store per block. Wave reduce via shfl_down
// (ordered contiguous ranges => valid for non-commutative op); 1 barrier.
// ---------------------------------------------------------------------------
__global__ __launch_bounds__(BLOCK)
void nerf_reduce(const float* __restrict__ alpha, const int* __restrict__ ray_id,
                 float2* __restrict__ agg, float* __restrict__ alphainv,
                 int N_ray, int n) {
    const int c = blockIdx.x;
    const int t = threadIdx.x;
    const long gstart = (long)c * CHUNK + (long)t * PER_THREAD;

    // alphainv default = cumprod[0] = (1-alpha[0])+1e-11 (ref: last_idx=0 for
    // empty rays). Rays with samples are overwritten by pass 2's scatter.
    {
        int gid = c * BLOCK + t;
        if (gid < N_ray) alphainv[gid] = (1.0f - alpha[0]) + 1e-11f;
    }

    Pair run; run.v = 1.0f; run.f = 0;
    int prev = (gstart > 0 && gstart < (long)n) ? ray_id[gstart - 1] : -1;
    const bool full = (gstart + PER_THREAD) <= (long)n;

    if (full) {
        #pragma unroll
        for (int q = 0; q < PER_THREAD / 4; ++q) {
            float4 av = *(const float4*)(alpha  + gstart + 4 * q);
            int4   rv = *(const int4*)  (ray_id + gstart + 4 * q);
            float aa[4] = {av.x, av.y, av.z, av.w};
            int   rr[4] = {rv.x, rv.y, rv.z, rv.w};
            #pragma unroll
            for (int j = 0; j < 4; ++j) {
                Pair e; e.v = (1.0f - aa[j]) + 1e-11f; e.f = (rr[j] != prev);
                prev = rr[j];
                run = seg_combine(run, e);
            }
        }
    } else if (gstart < (long)n) {
        for (int k = 0; k < PER_THREAD; ++k) {
            long g = gstart + k;
            if (g < n) {
                int r = ray_id[g];
                Pair e; e.v = (1.0f - alpha[g]) + 1e-11f; e.f = (r != prev);
                prev = r;
                run = seg_combine(run, e);
            }
        }
    }

    // wave-ordered tree reduce: lane t covers [t, t+2*off) after each step;
    // lane 0's dependency tree only consumes in-range lanes.
    #pragma unroll
    for (int off = 1; off < 64; off <<= 1) {
        Pair o;
        o.v = __shfl_down(run.v, off);
        o.f = __shfl_down(run.f, off);
        run = seg_combine(run, o);
    }

    __shared__ float s_wv[NWAVE];
    __shared__ int   s_wf[NWAVE];
    const int lane = t & 63, wid = t >> 6;
    if (lane == 0) { s_wv[wid] = run.v; s_wf[wid] = run.f; }
    __syncthreads();
    if (t == 0) {
        Pair acc; acc.v = s_wv[0]; acc.f = s_wf[0];
        #pragma unroll
        for (int w = 1; w < NWAVE; ++w) {
            Pair e; e.v = s_wv[w]; e.f = s_wf[w];
            acc = seg_combine(acc, e);
        }
        agg[c] = make_float2(acc.v, __int_as_float(acc.f));
    }
}

// generic fallback if N_ray exceeds pass-1 thread count (not hit at this size)
__global__ void nerf_init_rest(const float* __restrict__ alpha,
                               float* __restrict__ alphainv_tail, int count) {
    int i = blockIdx.x * blockDim.x + threadIdx.x;
    if (i < count) alphainv_tail[i] = (1.0f - alpha[0]) + 1e-11f;
}

// ---------------------------------------------------------------------------
// Pass 2: full scan + apply. Chunk prefix = plain backward read over agg[]
// until a reset flag (typically a single load of agg[c-1]). Wave scan via
// shfl_up; 1 barrier total.
// ---------------------------------------------------------------------------
__global__ __launch_bounds__(BLOCK)
void nerf_apply(const float* __restrict__ alpha, const int* __restrict__ ray_id,
                const float2* __restrict__ agg,
                float* __restrict__ weights, float* __restrict__ alphainv, int n) {
    __shared__ float s_wv[NWAVE];
    __shared__ int   s_wf[NWAVE];
    __shared__ float s_pv;
    __shared__ int   s_pf;

    const int c = blockIdx.x;
    const int t = threadIdx.x;
    const int lane = t & 63, wid = t >> 6;
    const long gstart = (long)c * CHUNK + (long)t * PER_THREAD;

    float a[PER_THREAD];
    int   rid[PER_THREAD];
    const bool full = (gstart + PER_THREAD) <= (long)n;

    if (full) {
        #pragma unroll
        for (int q = 0; q < PER_THREAD / 4; ++q) {
            float4 av = *(const float4*)(alpha  + gstart + 4 * q);
            int4   rv = *(const int4*)  (ray_id + gstart + 4 * q);
            a[4*q+0] = av.x; a[4*q+1] = av.y; a[4*q+2] = av.z; a[4*q+3] = av.w;
            rid[4*q+0] = rv.x; rid[4*q+1] = rv.y; rid[4*q+2] = rv.z; rid[4*q+3] = rv.w;
        }
    } else {
        #pragma unroll
        for (int k = 0; k < PER_THREAD; ++k) {
            long g = gstart + k;
            a[k]   = (g < n) ? alpha[g]  : 0.0f;
            rid[k] = (g < n) ? ray_id[g] : -2;
        }
    }
    const int prev0 = (gstart > 0 && gstart < (long)n) ? ray_id[gstart - 1] : -1;
    const int rid_next = ((gstart + PER_THREAD) < (long)n) ? ray_id[gstart + PER_THREAD] : -1;

    // ---- thread-local aggregate (values recomputed again in apply loop) ----
    Pair run; run.v = 1.0f; run.f = 0;
    {
        int prev = prev0;
        #pragma unroll
        for (int k = 0; k < PER_THREAD; ++k) {
            bool inb = (gstart + k) < (long)n;
            Pair e;
            e.v = inb ? ((1.0f - a[k]) + 1e-11f) : 1.0f;
            e.f = inb ? (rid[k] != prev ? 1 : 0) : 0;
            prev = rid[k];
            run = seg_combine(run, e);
        }
    }

    // ---- wave inclusive scan (shfl_up, ordered) ----
    Pair val = run;
    #pragma unroll
    for (int off = 1; off < 64; off <<= 1) {
        Pair o;
        o.v = __shfl_up(val.v, off);
        o.f = __shfl_up(val.f, off);
        if (lane >= off) val = seg_combine(o, val);
    }
    // lane-exclusive (within wave)
    Pair lexcl;
    {
        float ev = __shfl_up(val.v, 1);
        int   ef = __shfl_up(val.f, 1);
        if (lane == 0) { lexcl.v = 1.0f; lexcl.f = 0; }
        else           { lexcl.v = ev;   lexcl.f = ef; }
    }

    if (lane == 63) { s_wv[wid] = val.v; s_wf[wid] = val.f; }

    // ---- chunk prefix from pass-1 aggregates (plain loads, depth ~1) ----
    if (t == 0) {
        Pair pre; pre.v = 1.0f; pre.f = 0;
        for (int j = c - 1; j >= 0; --j) {
            float2 g = agg[j];
            Pair e; e.v = g.x; e.f = __float_as_int(g.y);
            pre = (j == c - 1) ? e : seg_combine(e, pre);
            if (pre.f) break;   // reset flag: earlier chunks can't contribute
        }
        s_pv = pre.v; s_pf = pre.f;
    }
    __syncthreads();

    // ---- compose exclusive prefix: chunk (+) earlier-waves (+) earlier-lanes
    Pair wexcl; wexcl.v = 1.0f; wexcl.f = 0;
    #pragma unroll
    for (int w = 0; w < NWAVE; ++w) {
        if (w < wid) {
            Pair e; e.v = s_wv[w]; e.f = s_wf[w];
            wexcl = seg_combine(wexcl, e);
        }
    }
    Pair cpre; cpre.v = s_pv; cpre.f = s_pf;
    Pair run2 = seg_combine(seg_combine(cpre, wexcl), lexcl);

    // ---- apply: trans(i) = running value BEFORE i == cumprod[i-1] ----
    {
        int prev = prev0;
        #pragma unroll
        for (int k = 0; k < PER_THREAD; ++k) {
            bool inb = (gstart + k) < (long)n;
            float om = (1.0f - a[k]) + 1e-11f;
            int   f  = inb ? (rid[k] != prev ? 1 : 0) : 0;
            prev = rid[k];
            float trans = run2.v;
            if (inb) {
                Pair e; e.v = om; e.f = f;
                run2 = seg_combine(run2, e);   // run2.v = cumprod[i]
            }
            a[k] = a[k] * trans;               // weights, in place
            int nxt = (k + 1 < PER_THREAD) ? rid[k + 1] : rid_next;
            if (inb && nxt != rid[k])
                alphainv[rid[k]] = run2.v;     // one writer per ray (sorted ids)
        }
    }

    if (full) {
        #pragma unroll
        for (int q = 0; q < PER_THREAD / 4; ++q) {
            float4 wv;
            wv.x = a[4*q+0]; wv.y = a[4*q+1]; wv.z = a[4*q+2]; wv.w = a[4*q+3];
            *(float4*)(weights + gstart + 4 * q) = wv;
        }
    } else {
        for (int k = 0; k < PER_THREAD; ++k) {
            long g = gstart + k;
            if (g < n) weights[g] = a[k];
        }
    }
}

extern "C" void kernel_launch(void* const* d_in, const int* in_sizes, int n_in,
                              void* d_out, int out_size, void* d_ws, size_t ws_size,
                              hipStream_t stream) {
    const float* alpha  = (const float*)d_in[0];
    const int*   ray_id = (const int*)d_in[1];
    const int n     = in_sizes[0];
    const int N_ray = out_size - n;          // avoids device read of d_in[2]

    float* weights  = (float*)d_out;
    float* alphainv = weights + n;
    float2* agg     = (float2*)d_ws;         // nchunks * 8B aggregates

    const int nchunks = (n + CHUNK - 1) / CHUNK;

    nerf_reduce<<<nchunks, BLOCK, 0, stream>>>(alpha, ray_id, agg, alphainv, N_ray, n);
    if (N_ray > nchunks * BLOCK) {           // not hit at this size; deterministic per call
        int extra = N_ray - nchunks * BLOCK;
        nerf_init_rest<<<(extra + BLOCK - 1) / BLOCK, BLOCK, 0, stream>>>(
            alpha, alphainv + nchunks * BLOCK, extra);
    }
    nerf_apply<<<nchunks, BLOCK, 0, stream>>>(alpha, ray_id, agg, weights, alphainv, n);
}